// Round 21
// baseline (144.471 us; speedup 1.0000x reference)
//
#include <hip/hip_runtime.h>
#include <hip/hip_bf16.h>

#define HEADS 8
#define HID 16
#define F1 128    // HEADS*HID
#define OUTD 64
#define BWL 7          // log2(bucket width)
#define BW 128         // dst-range per bucket
#define MAXBUK 512     // >= ceil(N/BW); N=50000 -> 391
#define BCAP 3584      // fixed bucket capacity (mean 2176 + 31 sigma)
#define CHUNK 2048     // edges per block in scatter (256 thr x 8)

typedef unsigned int uint;
typedef unsigned short ushort;
typedef __attribute__((ext_vector_type(8))) short bfrag;   // 8 bf16 (4 VGPR)
typedef __attribute__((ext_vector_type(4))) float f32x4;

__device__ __forceinline__ ushort f2bf(float f) {
  __hip_bfloat16 b = __float2bfloat16(f);
  return *reinterpret_cast<ushort*>(&b);
}
__device__ __forceinline__ float bf2f_lo(uint w) {
  return __uint_as_float((w & 0xFFFFu) << 16);
}
__device__ __forceinline__ float bf2f_hi(uint w) {
  return __uint_as_float(w & 0xFFFF0000u);
}
// ELU both bf16 halves of a packed uint
__device__ __forceinline__ uint elu2(uint u) {
  float lo = bf2f_lo(u), hi = bf2f_hi(u);
  lo = lo > 0.f ? lo : __expf(lo) - 1.f;
  hi = hi > 0.f ? hi : __expf(hi) - 1.f;
  return (uint)f2bf(lo) | ((uint)f2bf(hi) << 16);
}

// ---------------- D1: setup ----------------
// W1t[c][k] bf16 128x128; W2t[c][k] bf16 64x128.
// Wdt[j][k] 16x128: cols j<8 = as1-folded W1, j>=8 = ad1-folded (head j&7).
// Wd2t[j][k] 16x128: j=0 as2-folded W2, j=1 ad2-folded, j>=2 zero.
__global__ void k_wcvt(const float* __restrict__ W1, const float* __restrict__ W2,
                       const float* __restrict__ as1, const float* __restrict__ ad1,
                       const float* __restrict__ as2, const float* __restrict__ ad2,
                       ushort* __restrict__ W1t, ushort* __restrict__ W2t,
                       ushort* __restrict__ Wdt, ushort* __restrict__ Wd2t,
                       int* __restrict__ bukcur, int NBUK) {
  int o = blockIdx.x * 256 + threadIdx.x;
  if (o < F1 * F1) {
    int c = o >> 7, k = o & 127;
    W1t[o] = f2bf(W1[k * F1 + c]);
  } else if (o < F1 * F1 + OUTD * F1) {
    int i = o - F1 * F1;
    int c = i >> 7, k = i & 127;
    W2t[i] = f2bf(W2[k * OUTD + c]);
  } else if (o < F1 * F1 + OUTD * F1 + 2048) {
    int i = o - (F1 * F1 + OUTD * F1);
    int j = i >> 7, k = i & 127;
    const float* av = j < 8 ? as1 : ad1;
    int h = j & 7;
    float s = 0.f;
#pragma unroll
    for (int t = 0; t < HID; ++t)
      s = fmaf(W1[k * F1 + h * HID + t], av[h * HID + t], s);
    Wdt[i] = f2bf(s);
  } else if (o < F1 * F1 + OUTD * F1 + 4096) {
    int i = o - (F1 * F1 + OUTD * F1 + 2048);
    int j = i >> 7, k = i & 127;
    float s = 0.f;
    if (j < 2) {
      const float* av = j == 0 ? as2 : ad2;
      for (int c = 0; c < OUTD; ++c) s = fmaf(W2[k * OUTD + c], av[c], s);
    }
    Wd2t[i] = f2bf(s);
  } else {
    int i = o - (F1 * F1 + OUTD * F1 + 4096);
    if (i < NBUK) bukcur[i] = 0;
  }
}

// ---------------- D2: fused scatter (blocks [0,NCH)) + layer-1 MFMA GEMM ----------------
// gemm1: x staged bf16 in LDS (17KB); B-fragments (W1t, Wdt) read directly
// from global — L2-resident, shared by all blocks. 8 blocks/CU occupancy.
__global__ __launch_bounds__(256) void k_sg(
    const int* __restrict__ ei, int E, int N, int* __restrict__ bukcur,
    int* __restrict__ pairs,
    const float* __restrict__ x, const ushort* __restrict__ W1t,
    const ushort* __restrict__ Wdt,
    uint* __restrict__ h1b,
    float* __restrict__ a_src, float* __restrict__ a_dst, int NCH_) {
  __shared__ __align__(16) ushort xl[64 * 136];   // 17.4 KB (scatter hist aliases)
  int tx = threadIdx.x;

  if ((int)blockIdx.x < NCH_) {
    // ---------------- scatter ----------------
    int* hist = (int*)xl;
    hist[tx] = 0; hist[tx + 256] = 0;
    __syncthreads();
    long long e0 = (long long)blockIdx.x * CHUNK;
    int ET = E + N;
    int myP[8], myB[8];
#pragma unroll
    for (int i = 0; i < 8; ++i) {
      long long e = e0 + i * 256 + tx;
      if (e < ET) {
        int s = e < E ? ei[e] : (int)(e - E);
        int d = e < E ? ei[E + e] : (int)(e - E);
        myP[i] = s | ((d & (BW - 1)) << 20);
        myB[i] = d >> BWL;
        atomicAdd(&hist[myB[i]], 1);
      } else {
        myB[i] = -1;
      }
    }
    __syncthreads();
    for (int b = tx; b < MAXBUK; b += 256) {
      int c = hist[b];
      hist[b] = c ? (b * BCAP + atomicAdd(&bukcur[b], c)) : 0;
    }
    __syncthreads();
#pragma unroll
    for (int i = 0; i < 8; ++i) {
      if (myB[i] >= 0) {
        int pos = atomicAdd(&hist[myB[i]], 1);
        pairs[pos] = myP[i];
      }
    }
    return;
  }

  // ---------------- gemm1 ----------------
  int r0 = ((int)blockIdx.x - NCH_) * 64;
  {
    int row = tx & 63, kq = tx >> 6;
    bool act = (r0 + row) < N;
    const float4* xg = reinterpret_cast<const float4*>(x + (size_t)(r0 + row) * F1 + kq * 32);
#pragma unroll
    for (int j = 0; j < 4; ++j) {
      float4 va = act ? xg[2 * j]     : make_float4(0.f, 0.f, 0.f, 0.f);
      float4 vb = act ? xg[2 * j + 1] : make_float4(0.f, 0.f, 0.f, 0.f);
      uint4 pk;
      pk.x = (uint)f2bf(va.x) | ((uint)f2bf(va.y) << 16);
      pk.y = (uint)f2bf(va.z) | ((uint)f2bf(va.w) << 16);
      pk.z = (uint)f2bf(vb.x) | ((uint)f2bf(vb.y) << 16);
      pk.w = (uint)f2bf(vb.z) | ((uint)f2bf(vb.w) << 16);
      *reinterpret_cast<uint4*>(&xl[row * 136 + kq * 32 + j * 8]) = pk;
    }
  }
  __syncthreads();

  int w = tx >> 6, l = tx & 63;
  int lr = l & 15, lo = l >> 4;

  bfrag af[4];
#pragma unroll
  for (int ks = 0; ks < 4; ++ks)
    af[ks] = *reinterpret_cast<const bfrag*>(&xl[(w * 16 + lr) * 136 + ks * 32 + lo * 8]);

  f32x4 acc[8];
#pragma unroll
  for (int n0 = 0; n0 < 8; ++n0) {
    acc[n0] = (f32x4){0.f, 0.f, 0.f, 0.f};
#pragma unroll
    for (int ks = 0; ks < 4; ++ks) {
      bfrag bf = *reinterpret_cast<const bfrag*>(W1t + (n0 * 16 + lr) * F1 + ks * 32 + lo * 8);
      acc[n0] = __builtin_amdgcn_mfma_f32_16x16x32_bf16(af[ks], bf, acc[n0], 0, 0, 0);
    }
  }
  // attention dots via folded-weight MFMA tile (B from global Wdt, L2-hot)
  f32x4 dacc = (f32x4){0.f, 0.f, 0.f, 0.f};
#pragma unroll
  for (int ks = 0; ks < 4; ++ks) {
    bfrag bd = *reinterpret_cast<const bfrag*>(Wdt + lr * F1 + ks * 32 + lo * 8);
    dacc = __builtin_amdgcn_mfma_f32_16x16x32_bf16(af[ks], bd, dacc, 0, 0, 0);
  }

  ushort* tp = reinterpret_cast<ushort*>(h1b);
#pragma unroll
  for (int n0 = 0; n0 < 8; ++n0) {
    int cbase = n0 * 16 + lr;
#pragma unroll
    for (int r = 0; r < 4; ++r) {
      int row = r0 + w * 16 + lo * 4 + r;
      if (row < N) tp[(size_t)row * 128 + cbase] = f2bf(acc[n0][r]);
    }
  }
#pragma unroll
  for (int r = 0; r < 4; ++r) {
    int row = r0 + w * 16 + lo * 4 + r;
    if (row < N) {
      if (lr < 8) a_src[row * HEADS + lr] = dacc[r];
      else        a_dst[row * HEADS + (lr - 8)] = dacc[r];
    }
  }
}

// ---------------- D3: per-bucket fine CSR (512 threads) ----------------
__global__ __launch_bounds__(512) void k_csr(const int* __restrict__ pairs,
                                             const int* __restrict__ bukcur,
                                             int* __restrict__ off, int* __restrict__ offe,
                                             int* __restrict__ csr, int N) {
  __shared__ int cnt[BW];
  __shared__ int cur[BW];
  int b = blockIdx.x, t = threadIdx.x;
  int beg = b * BCAP, end = beg + bukcur[b];
  if (t < BW) cnt[t] = 0;
  __syncthreads();
  for (int j = beg + t; j < end; j += 512)
    atomicAdd(&cnt[(pairs[j] >> 20) & (BW - 1)], 1);
  __syncthreads();
  int my = t < BW ? cnt[t] : 0;
  for (int o = 1; o < BW; o <<= 1) {
    int v = (t < BW && t >= o) ? cnt[t - o] : 0;
    __syncthreads();
    if (t < BW) cnt[t] += v;
    __syncthreads();
  }
  if (t < BW) {
    int start = beg + cnt[t] - my;   // exclusive within bucket
    cur[t] = start;
    int d0 = b * BW + t;
    if (d0 < N) { off[d0] = start; offe[d0] = start + my; }
  }
  __syncthreads();
  for (int j = beg + t; j < end; j += 512) {
    int pr = pairs[j];
    int pos = atomicAdd(&cur[(pr >> 20) & (BW - 1)], 1);
    csr[pos] = pr & 0xFFFFF;
  }
}

// ---------------- D4: layer-1 aggregate (single full-row pass) ----------------
// 8 dsts/block (512 thr); 1 wave/dst; four 16-lane groups on alternating
// edges; lane owns 8 channels via uint4 (16x16B = 256B row); head = c4>>1;
// combine shfl_xor(16/32).
__global__ __launch_bounds__(512) void k_agg1(
    const int* __restrict__ off, const int* __restrict__ offe,
    const int* __restrict__ csr, const uint4* __restrict__ h1b4,
    const float* __restrict__ a_src, const float* __restrict__ a_dst,
    const float* __restrict__ b1, uint* __restrict__ out1b, int N) {
  int w = threadIdx.x >> 6, lane = threadIdx.x & 63;
  int g = lane >> 4, c4 = lane & 15;   // channels 8*c4..8*c4+7
  int h = c4 >> 1;
  int d = blockIdx.x * 8 + w;
  if (d >= N) return;
  int beg = off[d], end = offe[d];
  float adl = a_dst[d * HEADS + h];
  float a[8] = {0.f, 0.f, 0.f, 0.f, 0.f, 0.f, 0.f, 0.f};
  float den = 0.f;
  for (int j = beg + g; j < end; j += 4) {
    int s = csr[j];
    float v = a_src[s * HEADS + h] + adl;
    v = v >= 0.f ? v : 0.2f * v;
    float p = __expf(v);
    uint4 wd = h1b4[(size_t)s * 16 + c4];
    a[0] = fmaf(p, bf2f_lo(wd.x), a[0]);
    a[1] = fmaf(p, bf2f_hi(wd.x), a[1]);
    a[2] = fmaf(p, bf2f_lo(wd.y), a[2]);
    a[3] = fmaf(p, bf2f_hi(wd.y), a[3]);
    a[4] = fmaf(p, bf2f_lo(wd.z), a[4]);
    a[5] = fmaf(p, bf2f_hi(wd.z), a[5]);
    a[6] = fmaf(p, bf2f_lo(wd.w), a[6]);
    a[7] = fmaf(p, bf2f_hi(wd.w), a[7]);
    den += p;
  }
#pragma unroll
  for (int i = 0; i < 8; ++i) {
    a[i] += __shfl_xor(a[i], 16);
    a[i] += __shfl_xor(a[i], 32);
  }
  den += __shfl_xor(den, 16); den += __shfl_xor(den, 32);
  if (g == 0) {
    float inv = 1.f / den;   // self-loop guarantees den > 0
    float4 b0 = *reinterpret_cast<const float4*>(&b1[8 * c4]);
    float4 b1v = *reinterpret_cast<const float4*>(&b1[8 * c4 + 4]);
    uint4 o;
    o.x = (uint)f2bf(a[0] * inv + b0.x)  | ((uint)f2bf(a[1] * inv + b0.y) << 16);
    o.y = (uint)f2bf(a[2] * inv + b0.z)  | ((uint)f2bf(a[3] * inv + b0.w) << 16);
    o.z = (uint)f2bf(a[4] * inv + b1v.x) | ((uint)f2bf(a[5] * inv + b1v.y) << 16);
    o.w = (uint)f2bf(a[6] * inv + b1v.z) | ((uint)f2bf(a[7] * inv + b1v.w) << 16);
    *reinterpret_cast<uint4*>(&out1b[(size_t)d * 64 + 4 * c4]) = o;
  }
}

// ---------------- D5: layer 2 GEMM (MFMA bf16, ELU fused into staging) ----------------
// B-fragments (W2t, Wd2t) read directly from global (L2-hot, 16KB+4KB).
__global__ __launch_bounds__(256) void k_gemm2(
    const uint* __restrict__ out1b, const ushort* __restrict__ W2t,
    const ushort* __restrict__ Wd2t,
    uint* __restrict__ h2b, float* __restrict__ a_src2,
    float* __restrict__ a_dst2, int N) {
  __shared__ __align__(16) ushort xl[64 * 136];   // 17.4 KB
  int tx = threadIdx.x;
  int r0 = blockIdx.x * 64;

  {
    int row = tx & 63, kq = tx >> 6;
    bool act = (r0 + row) < N;
    const uint4* xg = reinterpret_cast<const uint4*>(out1b + (size_t)(r0 + row) * 64 + kq * 16);
#pragma unroll
    for (int j = 0; j < 4; ++j) {
      uint4 v = act ? xg[j] : make_uint4(0, 0, 0, 0);
      uint4 pk;
      pk.x = elu2(v.x);
      pk.y = elu2(v.y);
      pk.z = elu2(v.z);
      pk.w = elu2(v.w);
      *reinterpret_cast<uint4*>(&xl[row * 136 + kq * 32 + j * 8]) = pk;
    }
  }
  __syncthreads();

  int w = tx >> 6, l = tx & 63;
  int lr = l & 15, lo = l >> 4;

  bfrag af[4];
#pragma unroll
  for (int ks = 0; ks < 4; ++ks)
    af[ks] = *reinterpret_cast<const bfrag*>(&xl[(w * 16 + lr) * 136 + ks * 32 + lo * 8]);

  f32x4 acc[4];
#pragma unroll
  for (int n0 = 0; n0 < 4; ++n0) {
    acc[n0] = (f32x4){0.f, 0.f, 0.f, 0.f};
#pragma unroll
    for (int ks = 0; ks < 4; ++ks) {
      bfrag bf = *reinterpret_cast<const bfrag*>(W2t + (n0 * 16 + lr) * F1 + ks * 32 + lo * 8);
      acc[n0] = __builtin_amdgcn_mfma_f32_16x16x32_bf16(af[ks], bf, acc[n0], 0, 0, 0);
    }
  }
  f32x4 dacc = (f32x4){0.f, 0.f, 0.f, 0.f};
#pragma unroll
  for (int ks = 0; ks < 4; ++ks) {
    bfrag bd = *reinterpret_cast<const bfrag*>(Wd2t + lr * F1 + ks * 32 + lo * 8);
    dacc = __builtin_amdgcn_mfma_f32_16x16x32_bf16(af[ks], bd, dacc, 0, 0, 0);
  }

  ushort* tp = reinterpret_cast<ushort*>(h2b);
#pragma unroll
  for (int r = 0; r < 4; ++r) {
    int row = r0 + w * 16 + lo * 4 + r;
    if (row < N) {
#pragma unroll
      for (int n0 = 0; n0 < 4; ++n0)
        tp[(size_t)row * 64 + n0 * 16 + lr] = f2bf(acc[n0][r]);
      if (lr == 0) a_src2[row] = dacc[r];
      if (lr == 1) a_dst2[row] = dacc[r];
    }
  }
}

// ---------------- D6: layer 2 aggregate ----------------
__global__ void k_agg2(const int* __restrict__ off, const int* __restrict__ offe,
                       const int* __restrict__ csr,
                       const uint4* __restrict__ h2b4, const float* __restrict__ a_src2,
                       const float* __restrict__ a_dst2, const float* __restrict__ b2,
                       float* __restrict__ out, int N) {
  int w = threadIdx.x >> 6, lane = threadIdx.x & 63;
  int g = lane >> 3, c4 = lane & 7;   // channels 8*c4..8*c4+7
  int d = blockIdx.x * 4 + w;
  if (d >= N) return;
  int beg = off[d], end = offe[d];
  float adl = a_dst2[d];
  float a[8] = {0.f, 0.f, 0.f, 0.f, 0.f, 0.f, 0.f, 0.f};
  float den = 0.f;
  for (int j = beg + g; j < end; j += 8) {
    int s = csr[j];
    float v = a_src2[s] + adl;
    v = v >= 0.f ? v : 0.2f * v;
    float p = __expf(v);
    uint4 wd = h2b4[(size_t)s * 8 + c4];
    a[0] = fmaf(p, bf2f_lo(wd.x), a[0]);
    a[1] = fmaf(p, bf2f_hi(wd.x), a[1]);
    a[2] = fmaf(p, bf2f_lo(wd.y), a[2]);
    a[3] = fmaf(p, bf2f_hi(wd.y), a[3]);
    a[4] = fmaf(p, bf2f_lo(wd.z), a[4]);
    a[5] = fmaf(p, bf2f_hi(wd.z), a[5]);
    a[6] = fmaf(p, bf2f_lo(wd.w), a[6]);
    a[7] = fmaf(p, bf2f_hi(wd.w), a[7]);
    den += p;
  }
#pragma unroll
  for (int i = 0; i < 8; ++i) {
    a[i] += __shfl_xor(a[i], 8);
    a[i] += __shfl_xor(a[i], 16);
    a[i] += __shfl_xor(a[i], 32);
  }
  den += __shfl_xor(den, 8); den += __shfl_xor(den, 16); den += __shfl_xor(den, 32);
  if (g == 0) {
    float inv = 1.f / den;
    float4 b0 = *reinterpret_cast<const float4*>(&b2[8 * c4]);
    float4 b1v = *reinterpret_cast<const float4*>(&b2[8 * c4 + 4]);
    float4 o0, o1;
    o0.x = a[0] * inv + b0.x;  o0.y = a[1] * inv + b0.y;
    o0.z = a[2] * inv + b0.z;  o0.w = a[3] * inv + b0.w;
    o1.x = a[4] * inv + b1v.x; o1.y = a[5] * inv + b1v.y;
    o1.z = a[6] * inv + b1v.z; o1.w = a[7] * inv + b1v.w;
    *reinterpret_cast<float4*>(&out[(size_t)d * OUTD + 8 * c4]) = o0;
    *reinterpret_cast<float4*>(&out[(size_t)d * OUTD + 8 * c4 + 4]) = o1;
  }
}

extern "C" void kernel_launch(void* const* d_in, const int* in_sizes, int n_in,
                              void* d_out, int out_size, void* d_ws, size_t ws_size,
                              hipStream_t stream) {
  const float* x   = (const float*)d_in[0];
  const int*   ei  = (const int*)d_in[1];
  const float* W1  = (const float*)d_in[2];
  const float* as1 = (const float*)d_in[3];
  const float* ad1 = (const float*)d_in[4];
  const float* b1  = (const float*)d_in[5];
  const float* W2  = (const float*)d_in[6];
  const float* as2 = (const float*)d_in[7];
  const float* ad2 = (const float*)d_in[8];
  const float* b2  = (const float*)d_in[9];
  float* out = (float*)d_out;

  int N = in_sizes[0] / F1;
  int E = in_sizes[1] / 2;
  int ET = E + N;
  int NBUK = (N + BW - 1) / BW;       // 391 for N=50000 (<= MAXBUK)
  int NCH = (ET + CHUNK - 1) / CHUNK; // scatter blocks
  int NT = (N + 63) / 64;             // GEMM tiles (64 rows)
  int NB8 = (N + 7) / 8;              // agg1 blocks
  int NWC = (F1 * F1 + OUTD * F1 + 4096 + MAXBUK + 255) / 256;

  // workspace layout (16B-aligned chunks)
  char* p = (char*)d_ws;
  auto alloc = [&](size_t bytes) {
    char* q = p;
    p += (bytes + 15) & ~(size_t)15;
    return q;
  };
  int* bukcur  = (int*)alloc((size_t)NBUK * 4);
  int* off     = (int*)alloc((size_t)N * 4);
  int* offe    = (int*)alloc((size_t)N * 4);
  int* pairs   = (int*)alloc((size_t)NBUK * BCAP * 4);
  int* csr     = (int*)alloc((size_t)NBUK * BCAP * 4);
  ushort* W1t  = (ushort*)alloc((size_t)F1 * F1 * 2);
  ushort* W2t  = (ushort*)alloc((size_t)OUTD * F1 * 2);
  ushort* Wdt  = (ushort*)alloc((size_t)16 * F1 * 2);
  ushort* Wd2t = (ushort*)alloc((size_t)16 * F1 * 2);
  uint* h1b    = (uint*)alloc((size_t)N * 64 * 4);   // full 128-ch bf16 rows
  uint* h2b    = (uint*)alloc((size_t)N * 32 * 4);
  uint* out1b  = (uint*)alloc((size_t)N * 64 * 4);   // bf16-packed out1
  float* a_src1 = (float*)alloc((size_t)N * HEADS * 4);
  float* a_dst1 = (float*)alloc((size_t)N * HEADS * 4);
  float* a_src2 = (float*)alloc((size_t)N * 4);
  float* a_dst2 = (float*)alloc((size_t)N * 4);

  // D1: setup (W convert + folded dot-weights + bucket-cursor zero)
  hipLaunchKernelGGL(k_wcvt, dim3(NWC), dim3(256), 0, stream,
                     W1, W2, as1, ad1, as2, ad2, W1t, W2t, Wdt, Wd2t, bukcur, NBUK);
  // D2: scatter || gemm1 (block-range fused)
  hipLaunchKernelGGL(k_sg, dim3(NCH + NT), dim3(256), 0, stream,
                     ei, E, N, bukcur, pairs,
                     x, W1t, Wdt, h1b, a_src1, a_dst1, NCH);
  // D3: fine CSR
  hipLaunchKernelGGL(k_csr, dim3(NBUK), dim3(512), 0, stream,
                     pairs, bukcur, off, offe, csr, N);
  // D4: layer-1 aggregate (single full-row pass)
  hipLaunchKernelGGL(k_agg1, dim3(NB8), dim3(512), 0, stream,
                     off, offe, csr, (const uint4*)h1b,
                     a_src1, a_dst1, b1, out1b, N);
  // D5/D6: layer 2
  hipLaunchKernelGGL(k_gemm2, dim3(NT), dim3(256), 0, stream,
                     out1b, W2t, Wd2t, h2b, a_src2, a_dst2, N);
  hipLaunchKernelGGL(k_agg2, dim3((N + 3) / 4), dim3(256), 0, stream,
                     off, offe, csr, (const uint4*)h2b, a_src2, a_dst2, b2, out, N);
}

// Round 22
// 134.029 us; speedup vs baseline: 1.0779x; 1.0779x over previous
//
#include <hip/hip_runtime.h>
#include <hip/hip_bf16.h>

#define HEADS 8
#define HID 16
#define F1 128    // HEADS*HID
#define OUTD 64
#define BWL 7          // log2(bucket width)
#define BW 128         // dst-range per bucket
#define MAXBUK 512     // >= ceil(N/BW); N=50000 -> 391
#define BCAP 3584      // fixed bucket capacity (mean 2176 + 31 sigma)
#define CHUNK 2048     // edges per block in scatter (256 thr x 8)

typedef unsigned int uint;
typedef unsigned short ushort;
typedef __attribute__((ext_vector_type(8))) short bfrag;   // 8 bf16 (4 VGPR)
typedef __attribute__((ext_vector_type(4))) float f32x4;

__device__ __forceinline__ ushort f2bf(float f) {
  __hip_bfloat16 b = __float2bfloat16(f);
  return *reinterpret_cast<ushort*>(&b);
}
__device__ __forceinline__ float bf2f_lo(uint w) {
  return __uint_as_float((w & 0xFFFFu) << 16);
}
__device__ __forceinline__ float bf2f_hi(uint w) {
  return __uint_as_float(w & 0xFFFF0000u);
}
// ELU both bf16 halves of a packed uint
__device__ __forceinline__ uint elu2(uint u) {
  float lo = bf2f_lo(u), hi = bf2f_hi(u);
  lo = lo > 0.f ? lo : __expf(lo) - 1.f;
  hi = hi > 0.f ? hi : __expf(hi) - 1.f;
  return (uint)f2bf(lo) | ((uint)f2bf(hi) << 16);
}

// ---------------- D1: setup ----------------
// W1t[c][k] bf16 128x128; W2t[c][k] bf16 64x128.
// Wdt[j][k] 16x128: cols j<8 = as1-folded W1, j>=8 = ad1-folded (head j&7).
// Wd2t[j][k] 16x128: j=0 as2-folded W2, j=1 ad2-folded, j>=2 zero.
__global__ void k_wcvt(const float* __restrict__ W1, const float* __restrict__ W2,
                       const float* __restrict__ as1, const float* __restrict__ ad1,
                       const float* __restrict__ as2, const float* __restrict__ ad2,
                       ushort* __restrict__ W1t, ushort* __restrict__ W2t,
                       ushort* __restrict__ Wdt, ushort* __restrict__ Wd2t,
                       int* __restrict__ bukcur, int NBUK) {
  int o = blockIdx.x * 256 + threadIdx.x;
  if (o < F1 * F1) {
    int c = o >> 7, k = o & 127;
    W1t[o] = f2bf(W1[k * F1 + c]);
  } else if (o < F1 * F1 + OUTD * F1) {
    int i = o - F1 * F1;
    int c = i >> 7, k = i & 127;
    W2t[i] = f2bf(W2[k * OUTD + c]);
  } else if (o < F1 * F1 + OUTD * F1 + 2048) {
    int i = o - (F1 * F1 + OUTD * F1);
    int j = i >> 7, k = i & 127;
    const float* av = j < 8 ? as1 : ad1;
    int h = j & 7;
    float s = 0.f;
#pragma unroll
    for (int t = 0; t < HID; ++t)
      s = fmaf(W1[k * F1 + h * HID + t], av[h * HID + t], s);
    Wdt[i] = f2bf(s);
  } else if (o < F1 * F1 + OUTD * F1 + 4096) {
    int i = o - (F1 * F1 + OUTD * F1 + 2048);
    int j = i >> 7, k = i & 127;
    float s = 0.f;
    if (j < 2) {
      const float* av = j == 0 ? as2 : ad2;
      for (int c = 0; c < OUTD; ++c) s = fmaf(W2[k * OUTD + c], av[c], s);
    }
    Wd2t[i] = f2bf(s);
  } else {
    int i = o - (F1 * F1 + OUTD * F1 + 4096);
    if (i < NBUK) bukcur[i] = 0;
  }
}

// ---------------- D2: fused scatter (blocks [0,NCH)) + layer-1 MFMA GEMM ----------------
// gemm1: x + W1t staged bf16 in LDS (52KB); Wdt dot-tile (4KB) from global.
__global__ __launch_bounds__(256) void k_sg(
    const int* __restrict__ ei, int E, int N, int* __restrict__ bukcur,
    int* __restrict__ pairs,
    const float* __restrict__ x, const ushort* __restrict__ W1t,
    const ushort* __restrict__ Wdt,
    uint* __restrict__ h1b,
    float* __restrict__ a_src, float* __restrict__ a_dst, int NCH_) {
  __shared__ __align__(16) char smem[52224];   // 64*136*2 + 128*136*2 bytes
  int tx = threadIdx.x;

  if ((int)blockIdx.x < NCH_) {
    // ---------------- scatter ----------------
    int* hist = (int*)smem;
    hist[tx] = 0; hist[tx + 256] = 0;
    __syncthreads();
    long long e0 = (long long)blockIdx.x * CHUNK;
    int ET = E + N;
    int myP[8], myB[8];
#pragma unroll
    for (int i = 0; i < 8; ++i) {
      long long e = e0 + i * 256 + tx;
      if (e < ET) {
        int s = e < E ? ei[e] : (int)(e - E);
        int d = e < E ? ei[E + e] : (int)(e - E);
        myP[i] = s | ((d & (BW - 1)) << 20);
        myB[i] = d >> BWL;
        atomicAdd(&hist[myB[i]], 1);
      } else {
        myB[i] = -1;
      }
    }
    __syncthreads();
    for (int b = tx; b < MAXBUK; b += 256) {
      int c = hist[b];
      hist[b] = c ? (b * BCAP + atomicAdd(&bukcur[b], c)) : 0;
    }
    __syncthreads();
#pragma unroll
    for (int i = 0; i < 8; ++i) {
      if (myB[i] >= 0) {
        int pos = atomicAdd(&hist[myB[i]], 1);
        pairs[pos] = myP[i];
      }
    }
    return;
  }

  // ---------------- gemm1 ----------------
  ushort* xl = (ushort*)smem;          // [64*136]
  ushort* wl = xl + 64 * 136;          // [128*136]
  int r0 = ((int)blockIdx.x - NCH_) * 64;

  {
    int c = tx >> 1, k0 = (tx & 1) * 64;
    const uint4* g = reinterpret_cast<const uint4*>(W1t + c * F1 + k0);
#pragma unroll
    for (int j = 0; j < 8; ++j)
      *reinterpret_cast<uint4*>(&wl[c * 136 + k0 + j * 8]) = g[j];
  }
  {
    int row = tx & 63, kq = tx >> 6;
    bool act = (r0 + row) < N;
    const float4* xg = reinterpret_cast<const float4*>(x + (size_t)(r0 + row) * F1 + kq * 32);
#pragma unroll
    for (int j = 0; j < 4; ++j) {
      float4 va = act ? xg[2 * j]     : make_float4(0.f, 0.f, 0.f, 0.f);
      float4 vb = act ? xg[2 * j + 1] : make_float4(0.f, 0.f, 0.f, 0.f);
      uint4 pk;
      pk.x = (uint)f2bf(va.x) | ((uint)f2bf(va.y) << 16);
      pk.y = (uint)f2bf(va.z) | ((uint)f2bf(va.w) << 16);
      pk.z = (uint)f2bf(vb.x) | ((uint)f2bf(vb.y) << 16);
      pk.w = (uint)f2bf(vb.z) | ((uint)f2bf(vb.w) << 16);
      *reinterpret_cast<uint4*>(&xl[row * 136 + kq * 32 + j * 8]) = pk;
    }
  }
  __syncthreads();

  int w = tx >> 6, l = tx & 63;
  int lr = l & 15, lo = l >> 4;

  bfrag af[4];
#pragma unroll
  for (int ks = 0; ks < 4; ++ks)
    af[ks] = *reinterpret_cast<const bfrag*>(&xl[(w * 16 + lr) * 136 + ks * 32 + lo * 8]);

  f32x4 acc[8];
#pragma unroll
  for (int n0 = 0; n0 < 8; ++n0) {
    acc[n0] = (f32x4){0.f, 0.f, 0.f, 0.f};
#pragma unroll
    for (int ks = 0; ks < 4; ++ks) {
      bfrag bf = *reinterpret_cast<const bfrag*>(&wl[(n0 * 16 + lr) * 136 + ks * 32 + lo * 8]);
      acc[n0] = __builtin_amdgcn_mfma_f32_16x16x32_bf16(af[ks], bf, acc[n0], 0, 0, 0);
    }
  }
  // attention dots via folded-weight MFMA tile (B from global Wdt, L2-hot)
  f32x4 dacc = (f32x4){0.f, 0.f, 0.f, 0.f};
#pragma unroll
  for (int ks = 0; ks < 4; ++ks) {
    bfrag bd = *reinterpret_cast<const bfrag*>(Wdt + lr * F1 + ks * 32 + lo * 8);
    dacc = __builtin_amdgcn_mfma_f32_16x16x32_bf16(af[ks], bd, dacc, 0, 0, 0);
  }

  ushort* tp = reinterpret_cast<ushort*>(h1b);
#pragma unroll
  for (int n0 = 0; n0 < 8; ++n0) {
    int cbase = n0 * 16 + lr;
#pragma unroll
    for (int r = 0; r < 4; ++r) {
      int row = r0 + w * 16 + lo * 4 + r;
      if (row < N) tp[(size_t)row * 128 + cbase] = f2bf(acc[n0][r]);
    }
  }
#pragma unroll
  for (int r = 0; r < 4; ++r) {
    int row = r0 + w * 16 + lo * 4 + r;
    if (row < N) {
      if (lr < 8) a_src[row * HEADS + lr] = dacc[r];
      else        a_dst[row * HEADS + (lr - 8)] = dacc[r];
    }
  }
}

// ---------------- D3: per-bucket fine CSR (512 threads) ----------------
__global__ __launch_bounds__(512) void k_csr(const int* __restrict__ pairs,
                                             const int* __restrict__ bukcur,
                                             int* __restrict__ off, int* __restrict__ offe,
                                             int* __restrict__ csr, int N) {
  __shared__ int cnt[BW];
  __shared__ int cur[BW];
  int b = blockIdx.x, t = threadIdx.x;
  int beg = b * BCAP, end = beg + bukcur[b];
  if (t < BW) cnt[t] = 0;
  __syncthreads();
  for (int j = beg + t; j < end; j += 512)
    atomicAdd(&cnt[(pairs[j] >> 20) & (BW - 1)], 1);
  __syncthreads();
  int my = t < BW ? cnt[t] : 0;
  for (int o = 1; o < BW; o <<= 1) {
    int v = (t < BW && t >= o) ? cnt[t - o] : 0;
    __syncthreads();
    if (t < BW) cnt[t] += v;
    __syncthreads();
  }
  if (t < BW) {
    int start = beg + cnt[t] - my;   // exclusive within bucket
    cur[t] = start;
    int d0 = b * BW + t;
    if (d0 < N) { off[d0] = start; offe[d0] = start + my; }
  }
  __syncthreads();
  for (int j = beg + t; j < end; j += 512) {
    int pr = pairs[j];
    int pos = atomicAdd(&cur[(pr >> 20) & (BW - 1)], 1);
    csr[pos] = pr & 0xFFFFF;
  }
}

// ---------------- D4: layer-1 aggregate (single full-row pass) ----------------
// 8 dsts/block (512 thr); 1 wave/dst; four 16-lane groups on alternating
// edges; lane owns 8 channels via uint4 (16x16B = 256B row); head = c4>>1;
// combine shfl_xor(16/32).
__global__ __launch_bounds__(512) void k_agg1(
    const int* __restrict__ off, const int* __restrict__ offe,
    const int* __restrict__ csr, const uint4* __restrict__ h1b4,
    const float* __restrict__ a_src, const float* __restrict__ a_dst,
    const float* __restrict__ b1, uint* __restrict__ out1b, int N) {
  int w = threadIdx.x >> 6, lane = threadIdx.x & 63;
  int g = lane >> 4, c4 = lane & 15;   // channels 8*c4..8*c4+7
  int h = c4 >> 1;
  int d = blockIdx.x * 8 + w;
  if (d >= N) return;
  int beg = off[d], end = offe[d];
  float adl = a_dst[d * HEADS + h];
  float a[8] = {0.f, 0.f, 0.f, 0.f, 0.f, 0.f, 0.f, 0.f};
  float den = 0.f;
  for (int j = beg + g; j < end; j += 4) {
    int s = csr[j];
    float v = a_src[s * HEADS + h] + adl;
    v = v >= 0.f ? v : 0.2f * v;
    float p = __expf(v);
    uint4 wd = h1b4[(size_t)s * 16 + c4];
    a[0] = fmaf(p, bf2f_lo(wd.x), a[0]);
    a[1] = fmaf(p, bf2f_hi(wd.x), a[1]);
    a[2] = fmaf(p, bf2f_lo(wd.y), a[2]);
    a[3] = fmaf(p, bf2f_hi(wd.y), a[3]);
    a[4] = fmaf(p, bf2f_lo(wd.z), a[4]);
    a[5] = fmaf(p, bf2f_hi(wd.z), a[5]);
    a[6] = fmaf(p, bf2f_lo(wd.w), a[6]);
    a[7] = fmaf(p, bf2f_hi(wd.w), a[7]);
    den += p;
  }
#pragma unroll
  for (int i = 0; i < 8; ++i) {
    a[i] += __shfl_xor(a[i], 16);
    a[i] += __shfl_xor(a[i], 32);
  }
  den += __shfl_xor(den, 16); den += __shfl_xor(den, 32);
  if (g == 0) {
    float inv = 1.f / den;   // self-loop guarantees den > 0
    float4 b0 = *reinterpret_cast<const float4*>(&b1[8 * c4]);
    float4 b1v = *reinterpret_cast<const float4*>(&b1[8 * c4 + 4]);
    uint4 o;
    o.x = (uint)f2bf(a[0] * inv + b0.x)  | ((uint)f2bf(a[1] * inv + b0.y) << 16);
    o.y = (uint)f2bf(a[2] * inv + b0.z)  | ((uint)f2bf(a[3] * inv + b0.w) << 16);
    o.z = (uint)f2bf(a[4] * inv + b1v.x) | ((uint)f2bf(a[5] * inv + b1v.y) << 16);
    o.w = (uint)f2bf(a[6] * inv + b1v.z) | ((uint)f2bf(a[7] * inv + b1v.w) << 16);
    *reinterpret_cast<uint4*>(&out1b[(size_t)d * 64 + 4 * c4]) = o;
  }
}

// ---------------- D5: layer 2 GEMM (MFMA bf16, ELU fused into staging) ----------------
__global__ __launch_bounds__(256) void k_gemm2(
    const uint* __restrict__ out1b, const ushort* __restrict__ W2t,
    const ushort* __restrict__ Wd2t,
    uint* __restrict__ h2b, float* __restrict__ a_src2,
    float* __restrict__ a_dst2, int N) {
  __shared__ __align__(16) ushort xl[64 * 136];   // 17.0 KB
  __shared__ __align__(16) ushort wl[64 * 136];   // 17.0 KB
  int tx = threadIdx.x;
  int r0 = blockIdx.x * 64;

  {
    int c = tx & 63, k0 = (tx >> 6) * 32;
    const uint4* g = reinterpret_cast<const uint4*>(W2t + c * F1 + k0);
#pragma unroll
    for (int j = 0; j < 4; ++j)
      *reinterpret_cast<uint4*>(&wl[c * 136 + k0 + j * 8]) = g[j];
  }
  {
    int row = tx & 63, kq = tx >> 6;
    bool act = (r0 + row) < N;
    const uint4* xg = reinterpret_cast<const uint4*>(out1b + (size_t)(r0 + row) * 64 + kq * 16);
#pragma unroll
    for (int j = 0; j < 4; ++j) {
      uint4 v = act ? xg[j] : make_uint4(0, 0, 0, 0);
      uint4 pk;
      pk.x = elu2(v.x);
      pk.y = elu2(v.y);
      pk.z = elu2(v.z);
      pk.w = elu2(v.w);
      *reinterpret_cast<uint4*>(&xl[row * 136 + kq * 32 + j * 8]) = pk;
    }
  }
  __syncthreads();

  int w = tx >> 6, l = tx & 63;
  int lr = l & 15, lo = l >> 4;

  bfrag af[4];
#pragma unroll
  for (int ks = 0; ks < 4; ++ks)
    af[ks] = *reinterpret_cast<const bfrag*>(&xl[(w * 16 + lr) * 136 + ks * 32 + lo * 8]);

  f32x4 acc[4];
#pragma unroll
  for (int n0 = 0; n0 < 4; ++n0) {
    acc[n0] = (f32x4){0.f, 0.f, 0.f, 0.f};
#pragma unroll
    for (int ks = 0; ks < 4; ++ks) {
      bfrag bf = *reinterpret_cast<const bfrag*>(&wl[(n0 * 16 + lr) * 136 + ks * 32 + lo * 8]);
      acc[n0] = __builtin_amdgcn_mfma_f32_16x16x32_bf16(af[ks], bf, acc[n0], 0, 0, 0);
    }
  }
  f32x4 dacc = (f32x4){0.f, 0.f, 0.f, 0.f};
#pragma unroll
  for (int ks = 0; ks < 4; ++ks) {
    bfrag bd = *reinterpret_cast<const bfrag*>(Wd2t + lr * F1 + ks * 32 + lo * 8);
    dacc = __builtin_amdgcn_mfma_f32_16x16x32_bf16(af[ks], bd, dacc, 0, 0, 0);
  }

  ushort* tp = reinterpret_cast<ushort*>(h2b);
#pragma unroll
  for (int r = 0; r < 4; ++r) {
    int row = r0 + w * 16 + lo * 4 + r;
    if (row < N) {
#pragma unroll
      for (int n0 = 0; n0 < 4; ++n0)
        tp[(size_t)row * 64 + n0 * 16 + lr] = f2bf(acc[n0][r]);
      if (lr == 0) a_src2[row] = dacc[r];
      if (lr == 1) a_dst2[row] = dacc[r];
    }
  }
}

// ---------------- D6: layer 2 aggregate ----------------
// 8 dsts/block (512 thr); 1 wave/dst; eight 8-lane groups on alternating
// edges; lane owns 8 channels via uint4; combine shfl_xor(8/16/32).
__global__ __launch_bounds__(512) void k_agg2(
    const int* __restrict__ off, const int* __restrict__ offe,
    const int* __restrict__ csr,
    const uint4* __restrict__ h2b4, const float* __restrict__ a_src2,
    const float* __restrict__ a_dst2, const float* __restrict__ b2,
    float* __restrict__ out, int N) {
  int w = threadIdx.x >> 6, lane = threadIdx.x & 63;
  int g = lane >> 3, c4 = lane & 7;   // channels 8*c4..8*c4+7
  int d = blockIdx.x * 8 + w;
  if (d >= N) return;
  int beg = off[d], end = offe[d];
  float adl = a_dst2[d];
  float a[8] = {0.f, 0.f, 0.f, 0.f, 0.f, 0.f, 0.f, 0.f};
  float den = 0.f;
  for (int j = beg + g; j < end; j += 8) {
    int s = csr[j];
    float v = a_src2[s] + adl;
    v = v >= 0.f ? v : 0.2f * v;
    float p = __expf(v);
    uint4 wd = h2b4[(size_t)s * 8 + c4];
    a[0] = fmaf(p, bf2f_lo(wd.x), a[0]);
    a[1] = fmaf(p, bf2f_hi(wd.x), a[1]);
    a[2] = fmaf(p, bf2f_lo(wd.y), a[2]);
    a[3] = fmaf(p, bf2f_hi(wd.y), a[3]);
    a[4] = fmaf(p, bf2f_lo(wd.z), a[4]);
    a[5] = fmaf(p, bf2f_hi(wd.z), a[5]);
    a[6] = fmaf(p, bf2f_lo(wd.w), a[6]);
    a[7] = fmaf(p, bf2f_hi(wd.w), a[7]);
    den += p;
  }
#pragma unroll
  for (int i = 0; i < 8; ++i) {
    a[i] += __shfl_xor(a[i], 8);
    a[i] += __shfl_xor(a[i], 16);
    a[i] += __shfl_xor(a[i], 32);
  }
  den += __shfl_xor(den, 8); den += __shfl_xor(den, 16); den += __shfl_xor(den, 32);
  if (g == 0) {
    float inv = 1.f / den;
    float4 b0 = *reinterpret_cast<const float4*>(&b2[8 * c4]);
    float4 b1v = *reinterpret_cast<const float4*>(&b2[8 * c4 + 4]);
    float4 o0, o1;
    o0.x = a[0] * inv + b0.x;  o0.y = a[1] * inv + b0.y;
    o0.z = a[2] * inv + b0.z;  o0.w = a[3] * inv + b0.w;
    o1.x = a[4] * inv + b1v.x; o1.y = a[5] * inv + b1v.y;
    o1.z = a[6] * inv + b1v.z; o1.w = a[7] * inv + b1v.w;
    *reinterpret_cast<float4*>(&out[(size_t)d * OUTD + 8 * c4]) = o0;
    *reinterpret_cast<float4*>(&out[(size_t)d * OUTD + 8 * c4 + 4]) = o1;
  }
}

extern "C" void kernel_launch(void* const* d_in, const int* in_sizes, int n_in,
                              void* d_out, int out_size, void* d_ws, size_t ws_size,
                              hipStream_t stream) {
  const float* x   = (const float*)d_in[0];
  const int*   ei  = (const int*)d_in[1];
  const float* W1  = (const float*)d_in[2];
  const float* as1 = (const float*)d_in[3];
  const float* ad1 = (const float*)d_in[4];
  const float* b1  = (const float*)d_in[5];
  const float* W2  = (const float*)d_in[6];
  const float* as2 = (const float*)d_in[7];
  const float* ad2 = (const float*)d_in[8];
  const float* b2  = (const float*)d_in[9];
  float* out = (float*)d_out;

  int N = in_sizes[0] / F1;
  int E = in_sizes[1] / 2;
  int ET = E + N;
  int NBUK = (N + BW - 1) / BW;       // 391 for N=50000 (<= MAXBUK)
  int NCH = (ET + CHUNK - 1) / CHUNK; // scatter blocks
  int NT = (N + 63) / 64;             // GEMM tiles (64 rows)
  int NB8 = (N + 7) / 8;              // agg blocks (8 dsts/block)
  int NWC = (F1 * F1 + OUTD * F1 + 4096 + MAXBUK + 255) / 256;

  // workspace layout (16B-aligned chunks)
  char* p = (char*)d_ws;
  auto alloc = [&](size_t bytes) {
    char* q = p;
    p += (bytes + 15) & ~(size_t)15;
    return q;
  };
  int* bukcur  = (int*)alloc((size_t)NBUK * 4);
  int* off     = (int*)alloc((size_t)N * 4);
  int* offe    = (int*)alloc((size_t)N * 4);
  int* pairs   = (int*)alloc((size_t)NBUK * BCAP * 4);
  int* csr     = (int*)alloc((size_t)NBUK * BCAP * 4);
  ushort* W1t  = (ushort*)alloc((size_t)F1 * F1 * 2);
  ushort* W2t  = (ushort*)alloc((size_t)OUTD * F1 * 2);
  ushort* Wdt  = (ushort*)alloc((size_t)16 * F1 * 2);
  ushort* Wd2t = (ushort*)alloc((size_t)16 * F1 * 2);
  uint* h1b    = (uint*)alloc((size_t)N * 64 * 4);   // full 128-ch bf16 rows
  uint* h2b    = (uint*)alloc((size_t)N * 32 * 4);
  uint* out1b  = (uint*)alloc((size_t)N * 64 * 4);   // bf16-packed out1
  float* a_src1 = (float*)alloc((size_t)N * HEADS * 4);
  float* a_dst1 = (float*)alloc((size_t)N * HEADS * 4);
  float* a_src2 = (float*)alloc((size_t)N * 4);
  float* a_dst2 = (float*)alloc((size_t)N * 4);

  // D1: setup (W convert + folded dot-weights + bucket-cursor zero)
  hipLaunchKernelGGL(k_wcvt, dim3(NWC), dim3(256), 0, stream,
                     W1, W2, as1, ad1, as2, ad2, W1t, W2t, Wdt, Wd2t, bukcur, NBUK);
  // D2: scatter || gemm1 (block-range fused)
  hipLaunchKernelGGL(k_sg, dim3(NCH + NT), dim3(256), 0, stream,
                     ei, E, N, bukcur, pairs,
                     x, W1t, Wdt, h1b, a_src1, a_dst1, NCH);
  // D3: fine CSR
  hipLaunchKernelGGL(k_csr, dim3(NBUK), dim3(512), 0, stream,
                     pairs, bukcur, off, offe, csr, N);
  // D4: layer-1 aggregate (single full-row pass)
  hipLaunchKernelGGL(k_agg1, dim3(NB8), dim3(512), 0, stream,
                     off, offe, csr, (const uint4*)h1b,
                     a_src1, a_dst1, b1, out1b, N);
  // D5/D6: layer 2
  hipLaunchKernelGGL(k_gemm2, dim3(NT), dim3(256), 0, stream,
                     out1b, W2t, Wd2t, h2b, a_src2, a_dst2, N);
  hipLaunchKernelGGL(k_agg2, dim3(NB8), dim3(512), 0, stream,
                     off, offe, csr, (const uint4*)h2b, a_src2, a_dst2, b2, out, N);
}